// Round 8
// baseline (201.255 us; speedup 1.0000x reference)
//
#include <hip/hip_runtime.h>
#include <hip/hip_bf16.h>

#define K_CLS 20
#define HIN 480
#define WIN 640
#define NPIX (HIN * WIN)
#define C_ 512
#define H_ 30
#define W_ 40
#define HW_ (H_ * W_)
#define NB_ 5
#define CNT_THRESH 10000
// out layout (fp32): pool_x[2048], NB, N, x_cropped[6*4*512*30*40]
#define XCROP_ELEMS (6 * 4 * C_ * H_ * W_)
#define ELEMS_PER_SN (C_ * H_ * W_)            // 614400 = one (s,n) slice
#define OUT_TOTAL (2050 + XCROP_ELEMS)

#define NBLK_STATS 300                 // NPIX/4/256 exactly

// native clang vector types: __builtin_nontemporal_store rejects
// HIP_vector_type (R5 compile fail) but accepts ext_vector_type.
typedef float f32x2 __attribute__((ext_vector_type(2)));
typedef float f32x4 __attribute__((ext_vector_type(4)));

// fuse_k (R8): 2 dispatches total. plan_k removed — its reduce (300x100
// ints from L2, ~120KB) + 19-elem sort is cheap enough that EVERY fuse
// block recomputes it redundantly (512 blocks x 120KB = 61MB L2 ~ 1.8us
// aggregate), overlapped behind staging + the s=5 identity copy. No
// cross-block sync, no ws-poison hazard; stats->fuse visibility via
// dispatch ordering. Emission = R6's per-position VALU taps (fastest
// measured; R7's LDS tap tables coincided with +2.7us).
#define F_CPB 4                        // channels per block
#define F_CGRP (C_ / F_CPB)            // 128
#define F_TPB 512
#define F_BLOCKS (4 * F_CGRP)          // 512

// ws int layout: [block][cnt20|mnx20|mny20|mxx20|mxy20] * 300

__global__ void stats_k(const float* __restrict__ seg, int* __restrict__ ws) {
    __shared__ int s_cnt[K_CLS], s_mnx[K_CLS], s_mny[K_CLS], s_mxx[K_CLS], s_mxy[K_CLS];
    int t = threadIdx.x;
    if (t < K_CLS) { s_cnt[t] = 0; s_mnx[t] = WIN; s_mny[t] = HIN; s_mxx[t] = -1; s_mxy[t] = -1; }
    __syncthreads();

    int p = blockIdx.x * blockDim.x + t;                 // quad-pixel index, 0..76799
    const float4* base = (const float4*)(seg + (size_t)3 * K_CLS * NPIX) + p;
    float4 v = base[0];
    float b0 = v.x, b1 = v.y, b2 = v.z, b3 = v.w;
    int k0 = 0, k1 = 0, k2 = 0, k3 = 0;
    #pragma unroll
    for (int k = 1; k < K_CLS; k++) {                    // strict > : np.argmax tie-break
        float4 u = base[(size_t)k * (NPIX / 4)];
        if (u.x > b0) { b0 = u.x; k0 = k; }
        if (u.y > b1) { b1 = u.y; k1 = k; }
        if (u.z > b2) { b2 = u.z; k2 = k; }
        if (u.w > b3) { b3 = u.w; k3 = k; }
    }
    int x = (p * 4) % WIN, y = (p * 4) / WIN;            // quad never wraps a row (640%4==0)
    if (k0 == k1 && k1 == k2 && k2 == k3) {              // common case: uniform class
        atomicAdd(&s_cnt[k0], 4);
        atomicMin(&s_mnx[k0], x);     atomicMax(&s_mxx[k0], x + 3);
        atomicMin(&s_mny[k0], y);     atomicMax(&s_mxy[k0], y);
    } else {
        int ks[4] = {k0, k1, k2, k3};
        #pragma unroll
        for (int i = 0; i < 4; i++) {
            atomicAdd(&s_cnt[ks[i]], 1);
            atomicMin(&s_mnx[ks[i]], x + i);  atomicMax(&s_mxx[ks[i]], x + i);
            atomicMin(&s_mny[ks[i]], y);      atomicMax(&s_mxy[ks[i]], y);
        }
    }
    __syncthreads();
    if (t < 100) {                                       // per-block partial, plain store
        int a = t / 20, c = t % 20;
        int val = (a == 0) ? s_cnt[c] : (a == 1) ? s_mnx[c] : (a == 2) ? s_mny[c]
                : (a == 3) ? s_mxx[c] : s_mxy[c];
        ws[blockIdx.x * 100 + t] = val;
    }
}

__global__ __launch_bounds__(F_TPB) void fuse_k(const float* __restrict__ feat,
                      const int* __restrict__ ws,
                      const float* __restrict__ pool_x,
                      float* __restrict__ out) {
    __shared__ float sf[F_CPB * HW_];                    // 19.2 KB feat slice
    __shared__ int part[5][100];
    __shared__ int st[100];
    __shared__ int s_nb[NB_ * 4];                        // final boxes

    int t  = threadIdx.x;
    int n  = blockIdx.x / F_CGRP;                        // batch, 0..3
    int c0 = (blockIdx.x % F_CGRP) * F_CPB;              // channel group base

    // ---- phase A: stage (n, c0..c0+3) slice into LDS; fuse s=5 identity
    // copy (out slice 20+n has the same linear layout as feat).
    const float* src = feat + ((size_t)n * C_ + c0) * HW_;
    float* cdst = out + 2050 + (size_t)(20 + n) * ELEMS_PER_SN + (size_t)c0 * HW_;
    for (int i = t; i < (F_CPB * HW_) / 4; i += F_TPB) {
        f32x4 v = ((const f32x4*)src)[i];
        ((f32x4*)sf)[i] = v;
        // dest only 8B-aligned (2050%4==2) -> two f32x2 NT stores
        f32x2 lo = {v.x, v.y}, hi = {v.z, v.w};
        __builtin_nontemporal_store(lo, (f32x2*)(cdst + i * 4));
        __builtin_nontemporal_store(hi, (f32x2*)(cdst + i * 4 + 2));
    }
    if (blockIdx.x == 0) {                               // header: pool_x, NB, N
        for (int i = t; i < 1024; i += F_TPB)
            ((float2*)out)[i] = ((const float2*)pool_x)[i];
        if (t == 0) { out[2048] = 5.0f; out[2049] = 4.0f; }
    }

    // ---- phase P: redundant per-block plan (reduce 300 records + select)
    if (t < 500) {
        int c = t % 100, chunk = t / 100;                // 5 chunks x 60 records
        int a = c / 20;
        int acc = (a == 0) ? 0 : (a == 1) ? WIN : (a == 2) ? HIN : -1;
        #pragma unroll
        for (int i = 0; i < 60; i++) {
            int v = ws[(chunk * 60 + i) * 100 + c];
            if (a == 0)      acc += v;
            else if (a <= 2) acc = v < acc ? v : acc;
            else             acc = v > acc ? v : acc;
        }
        part[chunk][c] = acc;
    }
    __syncthreads();
    if (t < 100) {
        int a = t / 20;
        int acc = part[0][t];
        #pragma unroll
        for (int i = 1; i < 5; i++) {
            int v = part[i][t];
            if (a == 0)      acc += v;
            else if (a <= 2) acc = v < acc ? v : acc;
            else             acc = v > acc ? v : acc;
        }
        st[t] = acc;
    }
    __syncthreads();
    if (t == 0) {
        int* cnt = st;
        int* mnx = st + 20; int* mny = st + 40; int* mxx = st + 60; int* mxy = st + 80;

        // np.unique -> sorted present ids; drop smallest present id
        int firstp = -1;
        for (int i = 0; i < K_CLS; i++) if (cnt[i] > 0) { firstp = i; break; }
        int order[K_CLS]; int nc = 0;
        for (int i = 0; i < K_CLS; i++)
            if (cnt[i] > 0 && i != firstp) order[nc++] = i;

        // stable insertion sort, descending by count
        for (int i = 1; i < nc; i++) {
            int key = order[i]; int j = i - 1;
            while (j >= 0 && cnt[order[j]] < cnt[key]) { order[j + 1] = order[j]; j--; }
            order[j + 1] = key;
        }

        int nsel = 0;
        for (int i = 0; i < nc && nsel < NB_ - 2; i++) {
            int b = order[i];
            if (cnt[b] > CNT_THRESH) {
                s_nb[nsel * 4 + 0] = mnx[b] >> 4;
                s_nb[nsel * 4 + 1] = mny[b] >> 4;
                s_nb[nsel * 4 + 2] = mxx[b] >> 4;
                s_nb[nsel * 4 + 3] = mxy[b] >> 4;
                nsel++;
            }
        }
        const int bb[5][4] = {
            {W_ / 4, H_ / 4, 3 * W_ / 4, 3 * H_ / 4},
            {0, 0, W_ / 3, H_},
            {0, 0, W_, H_ / 3},
            {2 * W_ / 3, 0, W_, H_},
            {0, 2 * H_ / 3, W_, H_}
        };
        for (int i = 0; nsel < NB_; i++, nsel++) {
            s_nb[nsel * 4 + 0] = bb[i][0];
            s_nb[nsel * 4 + 1] = bb[i][1];
            s_nb[nsel * 4 + 2] = bb[i][2];
            s_nb[nsel * 4 + 3] = bb[i][3];
        }
    }
    __syncthreads();                                     // sf + s_nb ready

    // ---- phase E: emit 5 bilinear crop slices from the staged slice
    for (int b = 0; b < NB_; b++) {
        int x0 = s_nb[b * 4 + 0], y0 = s_nb[b * 4 + 1];
        int x1 = s_nb[b * 4 + 2], y1 = s_nb[b * 4 + 3];
        int iw = max(x1 - x0, 1), ih = max(y1 - y0, 1);
        int cb = y0 * W_ + x0;                           // crop base in channel slice
        float sx = (float)iw * (1.0f / (float)W_);
        float sy = (float)ih * (1.0f / (float)H_);
        float* ob = out + 2050 + (size_t)(5 * n + b) * ELEMS_PER_SN + (size_t)c0 * HW_;

        for (int hw = t; hw < HW_; hw += F_TPB) {
            int h = hw / W_;
            int w = hw - h * W_;

            // half-pixel-center bilinear; scale<=1 so antialias inert,
            // edge renorm == clamp. CLAMP ORDER (R1 bug): hi tap =
            // unclamped lo + 1, THEN clamp. fx,fy >= -0.5 -> lo_u >= -1.
            float fy  = ((float)h + 0.5f) * sy - 0.5f;
            float flY = floorf(fy);
            float ty  = fy - flY;
            int ylo_u = (int)flY;
            int ylo = max(ylo_u, 0);
            int yhi = min(ylo_u + 1, ih - 1);

            float fx  = ((float)w + 0.5f) * sx - 0.5f;
            float flX = floorf(fx);
            float tx  = fx - flX;
            int xlo_u = (int)flX;
            int xlo = max(xlo_u, 0);
            int xhi = min(xlo_u + 1, iw - 1);

            // indices within one channel slice; max (y1-1)*40+x1-1 <= 1199
            int i00 = cb + ylo * W_ + xlo, i01 = cb + ylo * W_ + xhi;
            int i10 = cb + yhi * W_ + xlo, i11 = cb + yhi * W_ + xhi;

            float* op = ob + hw;
            #pragma unroll
            for (int j = 0; j < F_CPB; j++) {            // taps shared by channels
                const float* sp = sf + j * HW_;          // j*4800B folds into ds imm
                float v00 = sp[i00], v01 = sp[i01];
                float v10 = sp[i10], v11 = sp[i11];
                float top = v00 + tx * (v01 - v00);      // 3-FMA lerp
                float bot = v10 + tx * (v11 - v10);
                __builtin_nontemporal_store(top + ty * (bot - top), op + j * HW_);
            }
        }
    }
}

extern "C" void kernel_launch(void* const* d_in, const int* in_sizes, int n_in,
                              void* d_out, int out_size, void* d_ws, size_t ws_size,
                              hipStream_t stream) {
    const float* seg    = (const float*)d_in[0];
    const float* feat   = (const float*)d_in[1];
    const float* pool_x = (const float*)d_in[2];
    float* out = (float*)d_out;
    int* ws = (int*)d_ws;

    stats_k<<<NBLK_STATS, 256, 0, stream>>>(seg, ws);
    fuse_k<<<F_BLOCKS, F_TPB, 0, stream>>>(feat, ws, pool_x, out);
}